// Round 2
// baseline (392.770 us; speedup 1.0000x reference)
//
#include <hip/hip_runtime.h>

// Bilinear grid sample, B=16 H=128 W=128 C=256 P=8192, fp32.
// One wave handles NS=8 consecutive samples. Indices are wave-uniform ->
// scalar loads; corner row base offsets are forced into SGPRs via
// readfirstlane so each 1 KiB corner read is global_load_dwordx4 with
// saddr base + lane*16 voffset. All 32 corner loads per wave are
// independent and issued before the first consume -> 32 KiB MLP per wave.

#define B_ 16
#define H_ 128
#define W_ 128
#define C_ 256
#define P_ 8192
#define NS 8              // samples per wave
#define WPB 4             // waves per block (block = 256 threads)

__global__ __launch_bounds__(256) void grid_sample_kernel(
    const float* __restrict__ in, const float* __restrict__ idx,
    float* __restrict__ out)
{
    const int lane = threadIdx.x & 63;
    const int wid  = __builtin_amdgcn_readfirstlane(threadIdx.x >> 6);
    const int wave = blockIdx.x * WPB + wid;
    const int s0   = wave * NS;                 // first sample for this wave

    const float2* __restrict__ idx2 = (const float2*)idx;

    int   offs[NS][4];    // scalar (SGPR) corner row offsets, in pixels
    float w[NS][4];       // blend weights (uniform)

#pragma unroll
    for (int k = 0; k < NS; ++k) {
        const int s = s0 + k;
        const int b = s >> 13;                  // P = 2^13
        const float2 ind = idx2[s];             // uniform addr -> s_load
        const float f0 = floorf(ind.x);
        const float f1 = floorf(ind.y);
        const int i0f = (int)f0;
        const int i1f = (int)f1;
        const int i0c = (int)ceilf(ind.x);
        const int i1c = (int)ceilf(ind.y);
        const float mx = ind.x - f0;
        const float my = ind.y - f1;
        w[k][0] = (1.f - mx) * (1.f - my);
        w[k][1] = mx * (1.f - my);
        w[k][2] = (1.f - mx) * my;
        w[k][3] = mx * my;
        const int bb = b * (H_ * W_);
        offs[k][0] = __builtin_amdgcn_readfirstlane(bb + i0f * W_ + i1f);
        offs[k][1] = __builtin_amdgcn_readfirstlane(bb + i0c * W_ + i1f);
        offs[k][2] = __builtin_amdgcn_readfirstlane(bb + i0f * W_ + i1c);
        offs[k][3] = __builtin_amdgcn_readfirstlane(bb + i0c * W_ + i1c);
    }

    // Issue all 32 independent 1 KiB corner loads.
    float4 v[NS][4];
#pragma unroll
    for (int k = 0; k < NS; ++k) {
#pragma unroll
        for (int c = 0; c < 4; ++c) {
            const float4* p = (const float4*)(in + (size_t)offs[k][c] * C_);
            v[k][c] = p[lane];
        }
    }

    // Blend + store in issue order (fine-grained vmcnt drain).
#pragma unroll
    for (int k = 0; k < NS; ++k) {
        float4 r;
        r.x = v[k][0].x * w[k][0] + v[k][1].x * w[k][1] +
              v[k][2].x * w[k][2] + v[k][3].x * w[k][3];
        r.y = v[k][0].y * w[k][0] + v[k][1].y * w[k][1] +
              v[k][2].y * w[k][2] + v[k][3].y * w[k][3];
        r.z = v[k][0].z * w[k][0] + v[k][1].z * w[k][1] +
              v[k][2].z * w[k][2] + v[k][3].z * w[k][3];
        r.w = v[k][0].w * w[k][0] + v[k][1].w * w[k][1] +
              v[k][2].w * w[k][2] + v[k][3].w * w[k][3];
        float4* o = (float4*)(out + (size_t)(s0 + k) * C_);
        o[lane] = r;
    }
}

extern "C" void kernel_launch(void* const* d_in, const int* in_sizes, int n_in,
                              void* d_out, int out_size, void* d_ws, size_t ws_size,
                              hipStream_t stream) {
    const float* in  = (const float*)d_in[0];   // (B,H,W,C) fp32
    const float* idx = (const float*)d_in[1];   // (B,P,2)   fp32
    float* out = (float*)d_out;                 // (B,P,C)   fp32

    const int n_samples = B_ * P_;              // 131072
    const int samples_per_block = WPB * NS;     // 32
    dim3 grid(n_samples / samples_per_block);   // 4096
    dim3 block(256);
    grid_sample_kernel<<<grid, block, 0, stream>>>(in, idx, out);
}